// Round 4
// baseline (8003.603 us; speedup 1.0000x reference)
//
#include <hip/hip_runtime.h>
#include <math.h>

#define NB 16
#define NC 512
#define NH 38
#define NW 50
#define NHW 1900          // 38*50
#define NPOS 30400        // 16*1900
#define NANCH 17100       // 1900*9
#define PRE_N 6000
#define POST_N 300
#define KTOT 4608         // 512*9
#define IMGH 608.0f
#define IMGW 800.0f

// ---------------------------------------------------------------------------
// Kernel 1: 3x3 conv (pad 1) + bias + ReLU, implicit GEMM 64co x 64pos,
// BK=8, per-thread 4x4 FP64 accumulators (numerics: ~correctly-rounded f32
// result, within 1 ulp of any blocked-f32 reference). Grid (30, 8, 16).
// ---------------------------------------------------------------------------
__global__ __launch_bounds__(256)
void conv_f64(const float* __restrict__ x, const float* __restrict__ w,
              const float* __restrict__ bias, float* __restrict__ out)
{
    const int b    = blockIdx.z;
    const int co0  = blockIdx.y * 64;
    const int pos0 = blockIdx.x * 64;

    __shared__ __align__(16) float As[8][68];   // [k][co]
    __shared__ __align__(16) float Bs[8][68];   // [k][pos]

    const int tid = threadIdx.x;
    const int ty  = tid >> 4;    // co group: co0 + ty*4 .. +3
    const int tx  = tid & 15;    // pos group: pos0 + tx*4 .. +3

    double acc[4][4];
#pragma unroll
    for (int m = 0; m < 4; ++m)
#pragma unroll
        for (int n = 0; n < 4; ++n) acc[m][n] = 0.0;

    const float* xb = x + (size_t)b * NC * NHW;

    for (int k0 = 0; k0 < KTOT; k0 += 8) {
        // stage A (weights): As[k][co] = w[co][k], k = ci*9 + ky*3 + kx
#pragma unroll
        for (int r = 0; r < 2; ++r) {
            const int idx = tid + r * 256;
            const int coi = idx >> 3, kk = idx & 7;
            As[kk][coi] = w[(size_t)(co0 + coi) * KTOT + k0 + kk];
        }
        // stage B (im2col): Bs[k][pos]
#pragma unroll
        for (int r = 0; r < 2; ++r) {
            const int idx = tid + r * 256;
            const int kk = idx >> 6, pi = idx & 63;
            const int k  = k0 + kk;
            const int ci = k / 9;
            const int rr = k - ci * 9;
            const int ky = rr / 3;
            const int kx = rr - ky * 3;
            const int p  = pos0 + pi;
            const int py = p / NW;
            const int px = p - py * NW;
            const int yy = py + ky - 1;
            const int xx = px + kx - 1;
            float v = 0.f;
            if (p < NHW && (unsigned)yy < (unsigned)NH && (unsigned)xx < (unsigned)NW)
                v = xb[(size_t)ci * NHW + yy * NW + xx];
            Bs[kk][pi] = v;
        }
        __syncthreads();
#pragma unroll
        for (int kk = 0; kk < 8; ++kk) {
            double av[4], bv[4];
#pragma unroll
            for (int m = 0; m < 4; ++m) av[m] = (double)As[kk][ty * 4 + m];
#pragma unroll
            for (int n = 0; n < 4; ++n) bv[n] = (double)Bs[kk][tx * 4 + n];
#pragma unroll
            for (int m = 0; m < 4; ++m)
#pragma unroll
                for (int n = 0; n < 4; ++n) acc[m][n] += av[m] * bv[n];
        }
        __syncthreads();
    }

#pragma unroll
    for (int m = 0; m < 4; ++m) {
        const int co = co0 + ty * 4 + m;
        const double bi = (double)bias[co];
        float* orow = out + ((size_t)b * NC + co) * NHW;
#pragma unroll
        for (int n = 0; n < 4; ++n) {
            const int pos = pos0 + tx * 4 + n;
            if (pos < NHW) {
                double v = acc[m][n] + bi;
                orow[pos] = (float)(v > 0.0 ? v : 0.0);
            }
        }
    }
}

// ---------------------------------------------------------------------------
// Kernel 2: head (18 cls + 36 reg 1x1) with FP64 accumulation, logits rounded
// to f32 (matching the reference's cls/reg f32 tensors), softmax in f64 from
// f32 logits, decode in f64 from f32 anchors/locs, geometry in f32.
// ---------------------------------------------------------------------------
__global__ __launch_bounds__(256)
void head_f64(const float* __restrict__ act,
              const float* __restrict__ cls_w, const float* __restrict__ cls_b,
              const float* __restrict__ reg_w, const float* __restrict__ reg_b,
              float* __restrict__ boxes, float* __restrict__ scores)
{
    const int p = blockIdx.x * 256 + threadIdx.x;
    if (p >= NPOS) return;
    const int b  = p / NHW;
    const int hw = p - b * NHW;

    const float* av = act + (size_t)b * NC * NHW + hw;

    double acc[54];
#pragma unroll
    for (int o = 0; o < 54; ++o) acc[o] = 0.0;

    for (int c = 0; c < NC; ++c) {
        const double v = (double)av[(size_t)c * NHW];
#pragma unroll
        for (int o = 0; o < 18; ++o) acc[o]      += v * (double)cls_w[o * NC + c];
#pragma unroll
        for (int o = 0; o < 36; ++o) acc[18 + o] += v * (double)reg_w[o * NC + c];
    }

    // f32 logits (= reference's cls tensor values to ~1 ulp)
    float lg[18];
#pragma unroll
    for (int o = 0; o < 18; ++o) lg[o] = (float)(acc[o] + (double)cls_b[o]);
    // f32 loc (= reference's reg tensor)
    float loc[36];
#pragma unroll
    for (int o = 0; o < 36; ++o) loc[o] = (float)(acc[18 + o] + (double)reg_b[o]);

    // softmax over 18 in f64 from the f32 logits
    double mx = -1e300;
#pragma unroll
    for (int o = 0; o < 18; ++o) mx = fmax(mx, (double)lg[o]);
    double sum = 0.0;
#pragma unroll
    for (int o = 0; o < 18; ++o) sum += exp((double)lg[o] - mx);
    const double inv = 1.0 / sum;

    const int hy = hw / NW;
    const int hx = hw - hy * NW;
    const float shy = (float)(hy * 16);
    const float shx = (float)(hx * 16);

    const double rats[3] = {0.5, 1.0, 2.0};
    const double scls[3] = {8.0, 16.0, 32.0};

#pragma unroll
    for (int a = 0; a < 9; ++a) {
        const int ir = a / 3, is = a - ir * 3;
        const double hh = 16.0 * scls[is] * sqrt(rats[ir]);
        const double wd = 16.0 * scls[is] * sqrt(1.0 / rats[ir]);
        // anchors exactly as reference: f32 base + f32 shift, f32 adds
        const float ay1 = (float)(8.0 - hh * 0.5) + shy;
        const float ax1 = (float)(8.0 - wd * 0.5) + shx;
        const float ay2 = (float)(8.0 + hh * 0.5) + shy;
        const float ax2 = (float)(8.0 + wd * 0.5) + shx;
        const float ahf = ay2 - ay1;                 // f32, as reference
        const float awf = ax2 - ax1;
        const float acy = ay1 + 0.5f * ahf;
        const float acx = ax1 + 0.5f * awf;

        // decode in f64 from the f32 ingredients, round corners once
        const double ah = (double)ahf, aw = (double)awf;
        const double dy = (double)loc[4 * a + 0];
        const double dx = (double)loc[4 * a + 1];
        const double dh = (double)loc[4 * a + 2];
        const double dw = (double)loc[4 * a + 3];
        const double cy = dy * ah + (double)acy;
        const double cx = dx * aw + (double)acx;
        const double bh = exp(dh) * ah;
        const double bw = exp(dw) * aw;
        float y1 = (float)(cy - 0.5 * bh);
        float x1 = (float)(cx - 0.5 * bw);
        float y2 = (float)(cy + 0.5 * bh);
        float x2 = (float)(cx + 0.5 * bw);
        // clip + min-size in f32, exactly as reference
        y1 = fminf(fmaxf(y1, 0.f), IMGH);
        y2 = fminf(fmaxf(y2, 0.f), IMGH);
        x1 = fminf(fmaxf(x1, 0.f), IMGW);
        x2 = fminf(fmaxf(x2, 0.f), IMGW);
        const bool keep = ((y2 - y1) >= 16.0f) && ((x2 - x1) >= 16.0f);

        float sc = (float)(exp((double)lg[2 * a + 1] - mx) * inv);
        if (!keep) sc = -INFINITY;

        const int n = hw * 9 + a;
        float4 bx; bx.x = y1; bx.y = x1; bx.z = y2; bx.w = x2;
        *reinterpret_cast<float4*>(&boxes[((size_t)b * NANCH + n) * 4]) = bx;
        scores[(size_t)b * NANCH + n] = sc;
    }
}

// ---------------------------------------------------------------------------
// Kernel 3: exact rank = #{j: s_j > s_i} + #{j: s_j == s_i, j < i}
// (== lax.top_k ordering). rank < 6000 -> scatter into sorted arrays.
// ---------------------------------------------------------------------------
__global__ __launch_bounds__(256)
void rank2(const float* __restrict__ scores, const float* __restrict__ boxes,
           float* __restrict__ sortedS, float* __restrict__ sortedB)
{
    const int b = blockIdx.y;
    const int i = blockIdx.x * 256 + threadIdx.x;
    if (i >= NANCH) return;
    const float si = scores[(size_t)b * NANCH + i];
    const float* sb = scores + (size_t)b * NANCH;
    int rank = 0;
    for (int j = 0; j < NANCH; ++j) {
        const float sj = sb[j];
        rank += (sj > si) || (sj == si && j < i);
    }
    if (rank < PRE_N) {
        sortedS[(size_t)b * PRE_N + rank] = si;
        const float4 bx = *reinterpret_cast<const float4*>(&boxes[((size_t)b * NANCH + i) * 4]);
        *reinterpret_cast<float4*>(&sortedB[((size_t)b * PRE_N + rank) * 4]) = bx;
    }
}

// ---------------------------------------------------------------------------
// Kernel 4: NMS as the literal reference scan: 300 steps; parallel argmax
// (ties -> lowest index) over masked scores, then IoU suppression (f32).
// One block (256 threads) per image.
// ---------------------------------------------------------------------------
__global__ __launch_bounds__(256)
void nms2(const float* __restrict__ sortedS, const float* __restrict__ sortedB,
          float* __restrict__ out)
{
    const int b   = blockIdx.x;
    const int tid = threadIdx.x;
    __shared__ float s[PRE_N];
    __shared__ float red_v[256];
    __shared__ int   red_i[256];

    for (int j = tid; j < PRE_N; j += 256)
        s[j] = sortedS[(size_t)b * PRE_N + j];
    __syncthreads();

    const float* BB = sortedB + (size_t)b * PRE_N * 4;

    for (int step = 0; step < POST_N; ++step) {
        float v = -INFINITY;
        int   li = 0x7fffffff;
        for (int j = tid; j < PRE_N; j += 256) {
            const float sv = s[j];
            if (sv > v || (sv == v && j < li)) { v = sv; li = j; }
        }
        red_v[tid] = v; red_i[tid] = li;
        __syncthreads();
        for (int off = 128; off > 0; off >>= 1) {
            if (tid < off) {
                const float ov = red_v[tid + off];
                const int   oi = red_i[tid + off];
                if (ov > red_v[tid] || (ov == red_v[tid] && oi < red_i[tid])) {
                    red_v[tid] = ov; red_i[tid] = oi;
                }
            }
            __syncthreads();
        }
        const int   im = red_i[0];
        const float mv = red_v[0];
        const bool  ok = (mv > -INFINITY);

        if (ok) {
            const float4 bi = *reinterpret_cast<const float4*>(&BB[(size_t)im * 4]);
            const float area_i = fmaxf(bi.z - bi.x, 0.f) * fmaxf(bi.w - bi.y, 0.f);
            if (tid == 0) {
                float* orow = out + ((size_t)b * POST_N + step) * 5;
                orow[0] = bi.x; orow[1] = bi.y; orow[2] = bi.z; orow[3] = bi.w;
                orow[4] = mv;
            }
            for (int j = tid; j < PRE_N; j += 256) {
                const float4 bj = *reinterpret_cast<const float4*>(&BB[(size_t)j * 4]);
                const float area_j = fmaxf(bj.z - bj.x, 0.f) * fmaxf(bj.w - bj.y, 0.f);
                const float yy1 = fmaxf(bi.x, bj.x);
                const float xx1 = fmaxf(bi.y, bj.y);
                const float yy2 = fminf(bi.z, bj.z);
                const float xx2 = fminf(bi.w, bj.w);
                const float inter = fmaxf(yy2 - yy1, 0.f) * fmaxf(xx2 - xx1, 0.f);
                const float iou = inter / (area_j + area_i - inter + 1e-9f);
                if (iou > 0.7f) s[j] = -INFINITY;
            }
            __syncthreads();
            if (tid == 0) s[im] = -INFINITY;
        } else {
            if (tid == 0) {
                float* orow = out + ((size_t)b * POST_N + step) * 5;
                orow[0] = 0.f; orow[1] = 0.f; orow[2] = 0.f; orow[3] = 0.f; orow[4] = 0.f;
            }
        }
        __syncthreads();
    }
}

// ---------------------------------------------------------------------------
static const float* pick_input(void* const* d_in, const int* in_sizes, int n_in,
                               int want, int fallback)
{
    for (int i = 0; i < n_in; ++i)
        if (in_sizes[i] == want) return (const float*)d_in[i];
    return (const float*)d_in[fallback];
}

extern "C" void kernel_launch(void* const* d_in, const int* in_sizes, int n_in,
                              void* d_out, int out_size, void* d_ws, size_t ws_size,
                              hipStream_t stream)
{
    const float* x       = pick_input(d_in, in_sizes, n_in, 15564800, 0);
    const float* share_w = pick_input(d_in, in_sizes, n_in, 2359296, 1);
    const float* share_b = pick_input(d_in, in_sizes, n_in, 512, 2);
    const float* cls_w   = pick_input(d_in, in_sizes, n_in, 9216, 3);
    const float* cls_b   = pick_input(d_in, in_sizes, n_in, 18, 4);
    const float* reg_w   = pick_input(d_in, in_sizes, n_in, 18432, 5);
    const float* reg_b   = pick_input(d_in, in_sizes, n_in, 36, 6);
    float* out = (float*)d_out;

    // workspace layout (floats); total 17,412,800 = 69.7 MB
    float* W = (float*)d_ws;
    float* act     = W;                   // 16*512*1900 = 15,564,800
    float* boxes   = W + 15564800;        // 16*17100*4 =  1,094,400
    float* scores  = W + 16659200;        // 16*17100   =    273,600
    float* sortedB = W + 16932800;        // 16*6000*4  =    384,000
    float* sortedS = W + 17316800;        // 16*6000    =     96,000

    conv_f64<<<dim3(30, 8, NB), 256, 0, stream>>>(x, share_w, share_b, act);

    head_f64<<<dim3(119), 256, 0, stream>>>(act, cls_w, cls_b, reg_w, reg_b,
                                            boxes, scores);

    rank2<<<dim3(67, 16), 256, 0, stream>>>(scores, boxes, sortedS, sortedB);

    nms2<<<dim3(16), 256, 0, stream>>>(sortedS, sortedB, out);
}